// Round 3
// baseline (1936.851 us; speedup 1.0000x reference)
//
#include <hip/hip_runtime.h>
#include <math.h>

// Problem constants (fixed shapes from reference setup_inputs)
#define NS   32      // batch
#define TS   1024    // time steps
#define KIN  2048    // INPUT_SIZE
#define RED  128     // REDUCED
#define HID  32      // HIDDEN
#define G3   96      // 3*HIDDEN
#define SEQ  8       // x.shape[1] — x data itself is never used

#define GX_FLOATS   (NS * TS * G3)          // 3,145,728 per partial buffer
#define WC_FLOATS   (G3 * KIN)              // 196,608

// fea_len may arrive as int32 or int64. int64 little-endian with values
// < 2^31 => odd int32 words are all zero.
__device__ __forceinline__ int load_len(const int* __restrict__ p, int n) {
    bool is64 = (p[1] == 0) && (p[3] == 0) && (p[5] == 0) && (p[7] == 0);
    if (is64) return (int)((const long long*)p)[n];
    return p[n];
}

__device__ __forceinline__ float fsig(float x) {
    return 1.0f / (1.0f + __expf(-x));
}
__device__ __forceinline__ float ftanh(float x) {
    float ax = fabsf(x);
    float e  = __expf(-2.0f * ax);
    float r  = (1.0f - e) / (1.0f + e);
    return copysignf(r, x);
}

// ---------------------------------------------------------------------------
// K1: W_comb[j][k] = sum_m W_ih[j][m] * W_ann[m][k];  b_comb[j] = b_ih[j] + W_ih[j]·b_ann
// ---------------------------------------------------------------------------
__global__ __launch_bounds__(256) void k_prep(
        const float* __restrict__ W_ann, const float* __restrict__ b_ann,
        const float* __restrict__ W_ih,  const float* __restrict__ b_ih,
        float* __restrict__ W_comb, float* __restrict__ b_comb) {
    if (blockIdx.x == 768) {
        int j = threadIdx.x;
        if (j < G3) {
            float acc = b_ih[j];
            #pragma unroll 8
            for (int m = 0; m < RED; ++m) acc += W_ih[j * RED + m] * b_ann[m];
            b_comb[j] = acc;
        }
        return;
    }
    int id = blockIdx.x * 256 + threadIdx.x;   // 0 .. 196607
    int j = id >> 11;          // /2048
    int k = id & (KIN - 1);
    float acc = 0.0f;
    #pragma unroll 8
    for (int m = 0; m < RED; ++m) acc += W_ih[j * RED + m] * W_ann[m * KIN + k];
    W_comb[(size_t)j * KIN + k] = acc;
}

// ---------------------------------------------------------------------------
// K2: gx_partial[ks][n][t][j] = fea[n][t][kslice] · W_comb[j][kslice] (+b_comb if ks==0)
// Tile 64t x 96j, K-chunks of 32 (23 KB LDS -> 6 blocks/CU cap), KS-way K-split.
// __launch_bounds__(256,4) caps VGPR at 128 -> 4 waves/SIMD -> 4 blocks/CU.
// Register prefetch is only 5 float4/thread now.
// ---------------------------------------------------------------------------
template<int KS>
__global__ __launch_bounds__(256, 4) void k_gemm(
        const float* __restrict__ fea, const int* __restrict__ flen,
        const float* __restrict__ W_comb, const float* __restrict__ b_comb,
        float* __restrict__ gx) {
    const int n  = blockIdx.x;
    const int by = blockIdx.y;
    const int tt = by & 15;
    const int ks = by >> 4;
    const int t0 = tt * 64;
    const int L  = load_len(flen, n) + SEQ;
    if (t0 >= L) return;   // scan never reads gx at t >= L

    const int KC     = KIN / KS;       // K elements this block covers
    const int NCH    = KC / 32;        // 32-wide chunks
    const int k_base = ks * KC;

    __shared__ float4 feaS[64][9];     // [t][k4], chunk=8 float4 +1 pad
    __shared__ float4 wS[96][9];       // [j][k4]

    const int tx = threadIdx.x;
    const int jg = tx & 15;            // fast dim -> j (coalesced stores)
    const int tg = tx >> 4;            // 0..15

    float4 pf[2], pw[3];
    // prefetch chunk 0: fea 64x8 f4 (2/thread), w 96x8 f4 (3/thread)
    {
        int k0 = k_base;
        #pragma unroll
        for (int p = 0; p < 2; ++p) {
            int fl = tx + p * 256; int row = fl >> 3, c4 = fl & 7;
            pf[p] = *(const float4*)(fea + ((size_t)(n * TS + t0 + row)) * KIN + k0 + c4 * 4);
        }
        #pragma unroll
        for (int p = 0; p < 3; ++p) {
            int fl = tx + p * 256; int row = fl >> 3, c4 = fl & 7;
            pw[p] = *(const float4*)(W_comb + (size_t)row * KIN + k0 + c4 * 4);
        }
    }

    float acc[4][6];
    #pragma unroll
    for (int i = 0; i < 4; ++i)
        #pragma unroll
        for (int jj = 0; jj < 6; ++jj) acc[i][jj] = 0.0f;

    #pragma unroll 1
    for (int kc = 0; kc < NCH; ++kc) {
        __syncthreads();               // prior readers done with LDS
        #pragma unroll
        for (int p = 0; p < 2; ++p) { int fl = tx + p * 256; feaS[fl >> 3][fl & 7] = pf[p]; }
        #pragma unroll
        for (int p = 0; p < 3; ++p) { int fl = tx + p * 256; wS[fl >> 3][fl & 7] = pw[p]; }
        __syncthreads();
        if (kc + 1 < NCH) {            // issue next chunk's loads; they fly over compute
            int k0 = k_base + (kc + 1) * 32;
            #pragma unroll
            for (int p = 0; p < 2; ++p) {
                int fl = tx + p * 256; int row = fl >> 3, c4 = fl & 7;
                pf[p] = *(const float4*)(fea + ((size_t)(n * TS + t0 + row)) * KIN + k0 + c4 * 4);
            }
            #pragma unroll
            for (int p = 0; p < 3; ++p) {
                int fl = tx + p * 256; int row = fl >> 3, c4 = fl & 7;
                pw[p] = *(const float4*)(W_comb + (size_t)row * KIN + k0 + c4 * 4);
            }
        }
        #pragma unroll
        for (int k4 = 0; k4 < 8; ++k4) {
            float4 a[4], w[6];
            #pragma unroll
            for (int i = 0; i < 4; ++i)  a[i] = feaS[tg + 16 * i][k4];
            #pragma unroll
            for (int jj = 0; jj < 6; ++jj) w[jj] = wS[jg + 16 * jj][k4];
            #pragma unroll
            for (int i = 0; i < 4; ++i)
                #pragma unroll
                for (int jj = 0; jj < 6; ++jj)
                    acc[i][jj] += a[i].x * w[jj].x + a[i].y * w[jj].y +
                                  a[i].z * w[jj].z + a[i].w * w[jj].w;
        }
    }

    float* gxo = gx + (size_t)ks * GX_FLOATS;
    #pragma unroll
    for (int i = 0; i < 4; ++i) {
        int t = t0 + tg + 16 * i;
        #pragma unroll
        for (int jj = 0; jj < 6; ++jj) {
            int j = jg + 16 * jj;
            float v = acc[i][jj];
            if (ks == 0) v += b_comb[j];
            gxo[((size_t)(n * TS + t)) * G3 + j] = v;
        }
    }
}

// ---------------------------------------------------------------------------
// K3: GRU scan + q + masked mean. One wave per sample.
// lane = kh*32 + j. kh also selects the K-split partial gx buffer: each half
// loads only ITS partial (3 dwords/step), and the partial-x contributions ride
// the same shfl_xor(32) that combines the half-K recurrent dots.
// Prefetch ring depth 8 (statically unrolled -> ring lives in fixed VGPRs,
// loads issued 8 steps = ~2500 cyc before use; HBM latency ~900 cyc hidden).
// ---------------------------------------------------------------------------
template<int KS>
__global__ __launch_bounds__(64) void k_scan(
        const float* __restrict__ gx, const int* __restrict__ flen,
        const float* __restrict__ W_hh, const float* __restrict__ b_hh,
        const float* __restrict__ W_q,  const float* __restrict__ b_q,
        float* __restrict__ out) {
    const int n    = blockIdx.x;
    const int lane = threadIdx.x;
    const int j    = lane & 31;
    const int kh   = lane >> 5;
    const int L    = load_len(flen, n) + SEQ;   // L >= 8 always
    const int sbase = kh << 4;

    // per-lane recurrent weights (this lane's K-half of rows r=j, z=32+j, n=64+j)
    float wr[16], wz[16], wn[16];
    {
        const float4* Wr4 = (const float4*)(W_hh + (size_t)(j)      * HID + sbase);
        const float4* Wz4 = (const float4*)(W_hh + (size_t)(32 + j) * HID + sbase);
        const float4* Wn4 = (const float4*)(W_hh + (size_t)(64 + j) * HID + sbase);
        #pragma unroll
        for (int p = 0; p < 4; ++p) {
            float4 v;
            v = Wr4[p]; wr[4*p] = v.x; wr[4*p+1] = v.y; wr[4*p+2] = v.z; wr[4*p+3] = v.w;
            v = Wz4[p]; wz[4*p] = v.x; wz[4*p+1] = v.y; wz[4*p+2] = v.z; wz[4*p+3] = v.w;
            v = Wn4[p]; wn[4*p] = v.x; wn[4*p+1] = v.y; wn[4*p+2] = v.z; wn[4*p+3] = v.w;
        }
    }
    const float br = b_hh[j], bz = b_hh[32 + j], bn = b_hh[64 + j];
    const float wq = W_q[j];
    const float bq = b_q[0];

    // kh selects the partial buffer (KS==2); for KS==1 both halves read buf 0
    const float* gbase = gx + (size_t)n * TS * G3
                       + ((KS == 2 && kh == 1) ? (size_t)GX_FLOATS : (size_t)0);
    // whether this lane contributes x-partials (KS==1: only kh==0, else doubled)
    const bool xon = (KS == 2) || (kh == 0);

    float rg[8][3];
    #pragma unroll
    for (int i = 0; i < 8; ++i) {
        const float* p = gbase + (size_t)i * G3;
        rg[i][0] = p[j]; rg[i][1] = p[32 + j]; rg[i][2] = p[64 + j];
    }

    float hv[16];
    #pragma unroll
    for (int i = 0; i < 16; ++i) hv[i] = 0.0f;
    float h = 0.0f, qacc = 0.0f;

    for (int tb = 0; tb < L; tb += 8) {
        #pragma unroll
        for (int i = 0; i < 8; ++i) {
            int t = tb + i;
            if (t >= L) break;                 // wave-uniform
            float xr = xon ? rg[i][0] : 0.0f;
            float xz = xon ? rg[i][1] : 0.0f;
            float xn = xon ? rg[i][2] : 0.0f;
            // refill slot i for t+8 (clip inside this sample; beyond-L values
            // are loaded but never consumed)
            {
                int tl = t + 8; if (tl > TS - 1) tl = TS - 1;
                const float* p = gbase + (size_t)tl * G3;
                rg[i][0] = p[j]; rg[i][1] = p[32 + j]; rg[i][2] = p[64 + j];
            }

            // half-K dots (2 accumulators per gate to shorten chains)
            float gr0 = 0.f, gr1 = 0.f, gz0 = 0.f, gz1 = 0.f, gn0 = 0.f, gn1 = 0.f;
            #pragma unroll
            for (int q2 = 0; q2 < 16; q2 += 2) {
                gr0 += wr[q2] * hv[q2];     gr1 += wr[q2+1] * hv[q2+1];
                gz0 += wz[q2] * hv[q2];     gz1 += wz[q2+1] * hv[q2+1];
                gn0 += wn[q2] * hv[q2];     gn1 += wn[q2+1] * hv[q2+1];
            }
            // fold x-partials into the cross-half combine
            float c0 = xr + gr0 + gr1;   // -> xr_tot + gr_tot
            float c1 = xz + gz0 + gz1;   // -> xz_tot + gz_tot
            float c2 = gn0 + gn1;        // -> gn_tot
            float c3 = xn;               // -> xn_tot
            c0 += __shfl_xor(c0, 32, 64);
            c1 += __shfl_xor(c1, 32, 64);
            c2 += __shfl_xor(c2, 32, 64);
            c3 += __shfl_xor(c3, 32, 64);

            float r    = fsig(c0 + br);
            float z    = fsig(c1 + bz);
            float nng  = ftanh(c3 + r * (c2 + bn));
            h = (1.0f - z) * nng + z * h;
            qacc += wq * h;

            // refresh hv from lanes 0..31 (h identical in both halves)
            #pragma unroll
            for (int q2 = 0; q2 < 16; ++q2) hv[q2] = __shfl(h, sbase + q2, 64);
        }
    }

    // every j counted twice (kh=0 and kh=1 lanes hold identical streams)
    #pragma unroll
    for (int off = 32; off > 0; off >>= 1) qacc += __shfl_xor(qacc, off, 64);
    if (lane == 0) out[n] = qacc * 0.5f / (float)L + bq;
}

// ---------------------------------------------------------------------------
extern "C" void kernel_launch(void* const* d_in, const int* in_sizes, int n_in,
                              void* d_out, int out_size, void* d_ws, size_t ws_size,
                              hipStream_t stream) {
    // setup_inputs order: x, fea, fea_len, W_ann, b_ann, W_ih, W_hh, b_ih, b_hh, W_q, b_q
    const float* fea   = (const float*)d_in[1];
    const int*   flen  = (const int*)  d_in[2];
    const float* W_ann = (const float*)d_in[3];
    const float* b_ann = (const float*)d_in[4];
    const float* W_ih  = (const float*)d_in[5];
    const float* W_hh  = (const float*)d_in[6];
    const float* b_ih  = (const float*)d_in[7];
    const float* b_hh  = (const float*)d_in[8];
    const float* W_q   = (const float*)d_in[9];
    const float* b_q   = (const float*)d_in[10];
    float* out = (float*)d_out;

    float* ws = (float*)d_ws;
    size_t need2 = ((size_t)2 * GX_FLOATS + WC_FLOATS + 256) * sizeof(float);
    bool ks2 = ws_size >= need2;     // ws_size fixed per session -> same path every call

    if (ks2) {
        float* gx     = ws;                          // 2 partial buffers, 25.2 MB
        float* W_comb = ws + 2 * GX_FLOATS;
        float* b_comb = W_comb + WC_FLOATS;
        k_prep<<<769, 256, 0, stream>>>(W_ann, b_ann, W_ih, b_ih, W_comb, b_comb);
        dim3 g2(NS, 32);                             // bx=n fastest, by=tt+16*ks
        k_gemm<2><<<g2, 256, 0, stream>>>(fea, flen, W_comb, b_comb, gx);
        k_scan<2><<<NS, 64, 0, stream>>>(gx, flen, W_hh, b_hh, W_q, b_q, out);
    } else {
        float* gx     = ws;                          // 12.6 MB
        float* W_comb = ws + GX_FLOATS;
        float* b_comb = W_comb + WC_FLOATS;
        k_prep<<<769, 256, 0, stream>>>(W_ann, b_ann, W_ih, b_ih, W_comb, b_comb);
        dim3 g2(NS, 16);
        k_gemm<1><<<g2, 256, 0, stream>>>(fea, flen, W_comb, b_comb, gx);
        k_scan<1><<<NS, 64, 0, stream>>>(gx, flen, W_hh, b_hh, W_q, b_q, out);
    }
}

// Round 4
// 762.821 us; speedup vs baseline: 2.5391x; 2.5391x over previous
//
#include <hip/hip_runtime.h>
#include <hip/hip_bf16.h>
#include <math.h>

// Problem constants (fixed shapes from reference setup_inputs)
#define NS   32      // batch
#define TS   1024    // time steps
#define KIN  2048    // INPUT_SIZE
#define RED  128     // REDUCED
#define HID  32      // HIDDEN
#define G3   96      // 3*HIDDEN
#define SEQ  8       // x.shape[1] — x data itself is never used

#define GX_FLOATS (NS * TS * G3)   // 3,145,728
#define W_ELEMS   (G3 * KIN)       // 196,608 bf16 elements per buffer

typedef __attribute__((ext_vector_type(8))) short  short8;   // 8 bf16 (4 VGPRs)
typedef __attribute__((ext_vector_type(4))) float  floatx4;  // MFMA accumulator

// fea_len may arrive as int32 or int64. int64 little-endian with values
// < 2^31 => odd int32 words are all zero.
__device__ __forceinline__ int load_len(const int* __restrict__ p, int n) {
    bool is64 = (p[1] == 0) && (p[3] == 0) && (p[5] == 0) && (p[7] == 0);
    if (is64) return (int)((const long long*)p)[n];
    return p[n];
}

__device__ __forceinline__ float fsig(float x) {
    return 1.0f / (1.0f + __expf(-x));
}
__device__ __forceinline__ float ftanh(float x) {
    float ax = fabsf(x);
    float e  = __expf(-2.0f * ax);
    float r  = (1.0f - e) / (1.0f + e);
    return copysignf(r, x);
}

// scalar fp32 -> bf16 (RNE) and back (exact)
__device__ __forceinline__ unsigned short f2bf(float x) {
    unsigned u = __float_as_uint(x);
    unsigned r = u + 0x7fffu + ((u >> 16) & 1u);
    return (unsigned short)(r >> 16);
}
__device__ __forceinline__ float bfu2f(unsigned short u) {
    return __uint_as_float(((unsigned)u) << 16);
}

// packed hi/lo split of 8 floats -> two bf16x8 fragments
__device__ __forceinline__ void cvt_hilo(const float* f, short8& hi, short8& lo) {
    #pragma unroll
    for (int p = 0; p < 4; ++p) {
        float2 fv = make_float2(f[2*p], f[2*p+1]);
        union { __hip_bfloat162 b2; unsigned short us[2]; } H, L;
        H.b2 = __float22bfloat162_rn(fv);
        float2 hb = __bfloat1622float2(H.b2);
        L.b2 = __float22bfloat162_rn(make_float2(fv.x - hb.x, fv.y - hb.y));
        hi[2*p] = (short)H.us[0]; hi[2*p+1] = (short)H.us[1];
        lo[2*p] = (short)L.us[0]; lo[2*p+1] = (short)L.us[1];
    }
}

// ---------------------------------------------------------------------------
// K1: W_comb = W_ih @ W_ann (96 x 2048), emitted as bf16 hi/lo pair;
//     b_comb[j] = b_ih[j] + W_ih[j]·b_ann.
// ---------------------------------------------------------------------------
__global__ __launch_bounds__(256) void k_prep(
        const float* __restrict__ W_ann, const float* __restrict__ b_ann,
        const float* __restrict__ W_ih,  const float* __restrict__ b_ih,
        unsigned short* __restrict__ Whi, unsigned short* __restrict__ Wlo,
        float* __restrict__ b_comb) {
    if (blockIdx.x == 768) {
        int j = threadIdx.x;
        if (j < G3) {
            float acc = b_ih[j];
            #pragma unroll 8
            for (int m = 0; m < RED; ++m) acc += W_ih[j * RED + m] * b_ann[m];
            b_comb[j] = acc;
        }
        return;
    }
    int id = blockIdx.x * 256 + threadIdx.x;   // 0 .. 196607
    int j = id >> 11;          // /2048
    int k = id & (KIN - 1);
    float acc = 0.0f;
    #pragma unroll 8
    for (int m = 0; m < RED; ++m) acc += W_ih[j * RED + m] * W_ann[m * KIN + k];
    unsigned short h = f2bf(acc);
    Whi[id] = h;
    Wlo[id] = f2bf(acc - bfu2f(h));
}

// ---------------------------------------------------------------------------
// K2: MFMA GEMM, no LDS / no barriers. gx[n][t][j] = fea[n][t][:]·Wc[j][:] + b_comb[j]
// computed as Ah·Bh + Ah·Bl + Al·Bh (bf16 hi/lo split, fp32 accumulate).
// Block: 256 thr = 4 waves; tile 128 t x 96 j; wave w owns rows [w*32, w*32+32).
// mfma_f32_16x16x32_bf16 layouts:
//   A: A[m=lane&15][k=(lane>>4)*8+i]  -> 32 contiguous bytes of one fea row/lane
//   B: B[k=(lane>>4)*8+i][n=lane&15]  -> 16 contiguous bytes of one W row/lane
//   D: row=(lane>>4)*4+reg, col=lane&15
// ---------------------------------------------------------------------------
__global__ __launch_bounds__(256) void k_gemm(
        const float* __restrict__ fea, const int* __restrict__ flen,
        const unsigned short* __restrict__ Whi,
        const unsigned short* __restrict__ Wlo,
        const float* __restrict__ b_comb,
        float* __restrict__ gx) {
    const int n  = blockIdx.x;
    const int t0 = blockIdx.y * 128;
    const int L  = load_len(flen, n) + SEQ;
    if (t0 >= L) return;   // scan never reads gx at t >= L

    const int tid  = threadIdx.x;
    const int w    = tid >> 6;      // wave 0..3
    const int ln   = tid & 63;
    const int mr   = ln & 15;       // row-within-frag / col-within-frag
    const int quad = ln >> 4;       // 0..3

    // A row base offsets (elements) for the wave's two 16-row M-frags
    const size_t arow0 = ((size_t)(n * TS + t0 + w * 32 + mr)) * KIN + quad * 8;
    const size_t arow1 = arow0 + (size_t)16 * KIN;
    // B row offsets per N-frag
    int boff[6];
    #pragma unroll
    for (int nf = 0; nf < 6; ++nf) boff[nf] = (nf * 16 + mr) * KIN + quad * 8;

    floatx4 acc[2][6];
    #pragma unroll
    for (int mf = 0; mf < 2; ++mf)
        #pragma unroll
        for (int nf = 0; nf < 6; ++nf) acc[mf][nf] = (floatx4){0.f, 0.f, 0.f, 0.f};

    #pragma unroll 1
    for (int c = 0; c < KIN / 64; ++c) {
        #pragma unroll
        for (int ks = 0; ks < 2; ++ks) {
            const int ko = c * 64 + ks * 32;
            float fa[8], fb[8];
            {
                float4 a0 = *(const float4*)(fea + arow0 + ko);
                float4 a1 = *(const float4*)(fea + arow0 + ko + 4);
                float4 b0 = *(const float4*)(fea + arow1 + ko);
                float4 b1 = *(const float4*)(fea + arow1 + ko + 4);
                fa[0]=a0.x; fa[1]=a0.y; fa[2]=a0.z; fa[3]=a0.w;
                fa[4]=a1.x; fa[5]=a1.y; fa[6]=a1.z; fa[7]=a1.w;
                fb[0]=b0.x; fb[1]=b0.y; fb[2]=b0.z; fb[3]=b0.w;
                fb[4]=b1.x; fb[5]=b1.y; fb[6]=b1.z; fb[7]=b1.w;
            }
            short8 ah0, al0, ah1, al1;
            cvt_hilo(fa, ah0, al0);
            cvt_hilo(fb, ah1, al1);
            #pragma unroll
            for (int nf = 0; nf < 6; ++nf) {
                short8 bh = *(const short8*)(Whi + boff[nf] + ko);
                short8 bl = *(const short8*)(Wlo + boff[nf] + ko);
                acc[0][nf] = __builtin_amdgcn_mfma_f32_16x16x32_bf16(ah0, bh, acc[0][nf], 0, 0, 0);
                acc[0][nf] = __builtin_amdgcn_mfma_f32_16x16x32_bf16(ah0, bl, acc[0][nf], 0, 0, 0);
                acc[0][nf] = __builtin_amdgcn_mfma_f32_16x16x32_bf16(al0, bh, acc[0][nf], 0, 0, 0);
                acc[1][nf] = __builtin_amdgcn_mfma_f32_16x16x32_bf16(ah1, bh, acc[1][nf], 0, 0, 0);
                acc[1][nf] = __builtin_amdgcn_mfma_f32_16x16x32_bf16(ah1, bl, acc[1][nf], 0, 0, 0);
                acc[1][nf] = __builtin_amdgcn_mfma_f32_16x16x32_bf16(al1, bh, acc[1][nf], 0, 0, 0);
            }
        }
    }

    // epilogue: D row=(lane>>4)*4+r, col=lane&15
    #pragma unroll
    for (int mf = 0; mf < 2; ++mf) {
        const int tbase = t0 + w * 32 + mf * 16 + quad * 4;
        #pragma unroll
        for (int nf = 0; nf < 6; ++nf) {
            const float bc = b_comb[nf * 16 + mr];
            float* gp = gx + ((size_t)(n * TS + tbase)) * G3 + nf * 16 + mr;
            #pragma unroll
            for (int r = 0; r < 4; ++r)
                gp[(size_t)r * G3] = acc[mf][nf][r] + bc;
        }
    }
}

// ---------------------------------------------------------------------------
// K3: GRU scan + q + masked mean. One wave per sample.
// lane = kh*32 + j. Branch-free 8-step blocks (predicated tail) so the
// depth-8 register prefetch ring fully unrolls; x-parts ride the same
// shfl_xor(32) that combines the half-K recurrent dots.
// ---------------------------------------------------------------------------
__global__ __launch_bounds__(64) void k_scan(
        const float* __restrict__ gx, const int* __restrict__ flen,
        const float* __restrict__ W_hh, const float* __restrict__ b_hh,
        const float* __restrict__ W_q,  const float* __restrict__ b_q,
        float* __restrict__ out) {
    const int n    = blockIdx.x;
    const int lane = threadIdx.x;
    const int j    = lane & 31;
    const int kh   = lane >> 5;
    const int L    = load_len(flen, n) + SEQ;   // L >= 8 always
    const int sbase = kh << 4;

    // per-lane recurrent weights (this lane's K-half of rows r=j, z=32+j, n=64+j)
    float wr[16], wz[16], wn[16];
    {
        const float4* Wr4 = (const float4*)(W_hh + (size_t)(j)      * HID + sbase);
        const float4* Wz4 = (const float4*)(W_hh + (size_t)(32 + j) * HID + sbase);
        const float4* Wn4 = (const float4*)(W_hh + (size_t)(64 + j) * HID + sbase);
        #pragma unroll
        for (int p = 0; p < 4; ++p) {
            float4 v;
            v = Wr4[p]; wr[4*p] = v.x; wr[4*p+1] = v.y; wr[4*p+2] = v.z; wr[4*p+3] = v.w;
            v = Wz4[p]; wz[4*p] = v.x; wz[4*p+1] = v.y; wz[4*p+2] = v.z; wz[4*p+3] = v.w;
            v = Wn4[p]; wn[4*p] = v.x; wn[4*p+1] = v.y; wn[4*p+2] = v.z; wn[4*p+3] = v.w;
        }
    }
    const float br = b_hh[j], bz = b_hh[32 + j], bn = b_hh[64 + j];
    const float wq = W_q[j];
    const float bq = b_q[0];

    const float* gbase = gx + (size_t)n * TS * G3;
    const bool xon = (kh == 0);   // only half 0 injects x (doubling avoided)

    float rg[8][3];
    #pragma unroll
    for (int i = 0; i < 8; ++i) {
        const float* p = gbase + (size_t)i * G3;
        rg[i][0] = p[j]; rg[i][1] = p[32 + j]; rg[i][2] = p[64 + j];
    }

    float hv[16];
    #pragma unroll
    for (int i = 0; i < 16; ++i) hv[i] = 0.0f;
    float h = 0.0f, qacc = 0.0f;

    for (int tb = 0; tb < L; tb += 8) {
        #pragma unroll
        for (int i = 0; i < 8; ++i) {
            const int t = tb + i;
            float xr = xon ? rg[i][0] : 0.0f;
            float xz = xon ? rg[i][1] : 0.0f;
            float xn = xon ? rg[i][2] : 0.0f;
            // refill slot i for t+8 (clip; beyond-L garbage never consumed)
            {
                int tl = t + 8; if (tl > TS - 1) tl = TS - 1;
                const float* p = gbase + (size_t)tl * G3;
                rg[i][0] = p[j]; rg[i][1] = p[32 + j]; rg[i][2] = p[64 + j];
            }

            // half-K dots (2 accumulators per gate to shorten chains)
            float gr0 = 0.f, gr1 = 0.f, gz0 = 0.f, gz1 = 0.f, gn0 = 0.f, gn1 = 0.f;
            #pragma unroll
            for (int q2 = 0; q2 < 16; q2 += 2) {
                gr0 += wr[q2] * hv[q2];     gr1 += wr[q2+1] * hv[q2+1];
                gz0 += wz[q2] * hv[q2];     gz1 += wz[q2+1] * hv[q2+1];
                gn0 += wn[q2] * hv[q2];     gn1 += wn[q2+1] * hv[q2+1];
            }
            float c0 = xr + gr0 + gr1;
            float c1 = xz + gz0 + gz1;
            float c2 = gn0 + gn1;
            float c3 = xn;
            c0 += __shfl_xor(c0, 32, 64);
            c1 += __shfl_xor(c1, 32, 64);
            c2 += __shfl_xor(c2, 32, 64);
            c3 += __shfl_xor(c3, 32, 64);

            float r    = fsig(c0 + br);
            float z    = fsig(c1 + bz);
            float nng  = ftanh(c3 + r * (c2 + bn));
            float hnew = (1.0f - z) * nng + z * h;
            if (t < L) {                   // wave-uniform predicate
                h = hnew;
                qacc += wq * hnew;
            }

            // refresh hv from lanes 0..31 (h identical in both halves)
            #pragma unroll
            for (int q2 = 0; q2 < 16; ++q2) hv[q2] = __shfl(h, sbase + q2, 64);
        }
    }

    // every j counted twice (kh=0 and kh=1 lanes hold identical streams)
    #pragma unroll
    for (int off = 32; off > 0; off >>= 1) qacc += __shfl_xor(qacc, off, 64);
    if (lane == 0) out[n] = qacc * 0.5f / (float)L + bq;
}

// ---------------------------------------------------------------------------
extern "C" void kernel_launch(void* const* d_in, const int* in_sizes, int n_in,
                              void* d_out, int out_size, void* d_ws, size_t ws_size,
                              hipStream_t stream) {
    // setup_inputs order: x, fea, fea_len, W_ann, b_ann, W_ih, W_hh, b_ih, b_hh, W_q, b_q
    const float* fea   = (const float*)d_in[1];
    const int*   flen  = (const int*)  d_in[2];
    const float* W_ann = (const float*)d_in[3];
    const float* b_ann = (const float*)d_in[4];
    const float* W_ih  = (const float*)d_in[5];
    const float* W_hh  = (const float*)d_in[6];
    const float* b_ih  = (const float*)d_in[7];
    const float* b_hh  = (const float*)d_in[8];
    const float* W_q   = (const float*)d_in[9];
    const float* b_q   = (const float*)d_in[10];
    float* out = (float*)d_out;

    // ws layout: gx fp32 | Whi bf16 | Wlo bf16 | b_comb   (~13.4 MB total)
    float*          ws_f   = (float*)d_ws;
    float*          gx     = ws_f;
    unsigned short* Whi    = (unsigned short*)(ws_f + GX_FLOATS);
    unsigned short* Wlo    = Whi + W_ELEMS;
    float*          b_comb = (float*)(Wlo + W_ELEMS);

    k_prep<<<769, 256, 0, stream>>>(W_ann, b_ann, W_ih, b_ih, Whi, Wlo, b_comb);

    dim3 g2(NS, TS / 128);               // (32 samples, 8 t-tiles of 128)
    k_gemm<<<g2, 256, 0, stream>>>(fea, flen, Whi, Wlo, b_comb, gx);

    k_scan<<<NS, 64, 0, stream>>>(gx, flen, W_hh, b_hh, W_q, b_q, out);
}